// Round 1
// 300.752 us; speedup vs baseline: 1.1109x; 1.1109x over previous
//
#include <hip/hip_runtime.h>

// R6: attn latency attack.
//  - Q fragments hoisted to registers (qt LDS reads removed from the chunk loop).
//  - LDS 45056 -> 28672 B (qt overlaid on kt, sP halved via kb-split same-wave P round-trip)
//    => 4 blocks/CU (16 waves) instead of 3 (12), and 2048 blocks = 2 exact dispatch rounds.
//  - Register prefetch of next chunk's K/V (T14): global latency hidden under compute.
//  - exp2-domain softmax (log2e folded into Q proj outscale) + defer-max rescale (THR=8).
// f32 I/O; bf16 internals; f32 softmax/accum. All MFMA LDS tiles in fragment order
// (granule index == reading lane -> conflict-free ds_read_b128).

typedef float  f32x4  __attribute__((ext_vector_type(4)));
typedef __bf16 bf16;
typedef __bf16 bf16x8 __attribute__((ext_vector_type(8)));

#define B_   16
#define D_   192
#define T_   4096
#define BANK 1000
#define SP   1024
#define DK   96
#define SCALE 0.10206207261596577f   // 1/sqrt(96)
#define LOG2E 1.4426950408889634f

// ---------------- K/V projection (tiny) ----------------
// ktg: [h][1024 s][96 i]   vtg: [h][96 i][1024 s]
__global__ __launch_bounds__(256) void kv_kernel(
    const float* __restrict__ mb, const float* __restrict__ Wk, const float* __restrict__ bk,
    const float* __restrict__ Wv, const float* __restrict__ bv,
    bf16* __restrict__ ktg, bf16* __restrict__ vtg) {
  int s = blockIdx.x * 256 + threadIdx.x;
  int o = blockIdx.y;
  int h = o / DK, i = o % DK;
  float ak = 0.f, av = 0.f;
  if (s < BANK) {
    ak = bk[o]; av = bv[o];
    for (int c = 0; c < D_; ++c) {
      float m = mb[c * BANK + s];
      ak += Wk[o * D_ + c] * m;
      av += Wv[o * D_ + c] * m;
    }
  }
  ktg[(size_t)(h * SP + s) * DK + i] = (bf16)ak;
  vtg[(size_t)(h * DK + i) * SP + s] = (bf16)av;
}

// ---------------- z transpose: z f32 [b][c][t] -> zT bf16 [b][t][c] ----------------
__global__ __launch_bounds__(256) void zt_kernel(const float* __restrict__ z,
                                                 bf16* __restrict__ zT) {
  __shared__ __align__(16) bf16 sT[64 * 200];
  const int tid = threadIdx.x;
  const int t0 = blockIdx.x * 64, b = blockIdx.y;
#pragma unroll
  for (int it = 0; it < 48; ++it) {          // 192c x 64t, coalesced along t
    int e = tid + 256 * it;
    int c = e >> 6, tl = e & 63;
    sT[tl * 200 + c] = (bf16)z[((size_t)b * D_ + c) * T_ + t0 + tl];
  }
  __syncthreads();
#pragma unroll
  for (int it = 0; it < 6; ++it) {           // 1536 granules of 8 bf16
    int g = tid + 256 * it;
    int tl = g / 24, c8 = (g % 24) * 8;
    bf16x8 v = *(const bf16x8*)&sT[tl * 200 + c8];
    *(bf16x8*)&zT[((size_t)b * T_ + t0 + tl) * D_ + c8] = v;
  }
}

// ---------------- MFMA projection: Y[b][o][t] = W · X + bias, times outscale ----------------
// XT bf16 [b][t][192 c]; W f32 [o][c]; Y f32 [b][o][t].
// Block: 64 o x 256 t; wave = 64 t (mt 0..3) x 64 o (nt 0..3). K chunks of 32.
__global__ __launch_bounds__(256) void proj_kernel(
    const bf16* __restrict__ XT, const float* __restrict__ W,
    const float* __restrict__ bias, float* __restrict__ Y, float outscale) {
  __shared__ __align__(16) char smem[40960];
  bf16* sA = (bf16*)smem;                    // per-chunk [16 tg][64 lane][8] = 16384 B
  bf16* sB = (bf16*)(smem + 16384);          // [6 kb][4 nt][64 lane][8]     = 24576 B
  float* sE = (float*)smem;                  // epilogue overlay: 4 waves x [16][68] f32

  const int tid = threadIdx.x;
  const int t0 = blockIdx.x * 256, o0 = blockIdx.y * 64, b = blockIdx.z;
  const int lane = tid & 63, wv = tid >> 6;
  const int quad = lane >> 4, l15 = lane & 15;

  // stage W (whole 64o x 192c) as packed B-frags, f32 -> bf16
#pragma unroll
  for (int r = 0; r < 6; ++r) {
    int g = tid + 256 * r;                   // [kb][nt][lane]
    int kb = g >> 8, nt = (g >> 6) & 3, qd = (g >> 4) & 3, l5 = g & 15;
    const float* wp = &W[(o0 + nt * 16 + l5) * D_ + kb * 32 + qd * 8];
    f32x4 wa = *(const f32x4*)wp, wb = *(const f32x4*)(wp + 4);
    bf16x8 pk;
#pragma unroll
    for (int u = 0; u < 4; ++u) { pk[u] = (bf16)wa[u]; pk[4 + u] = (bf16)wb[u]; }
    *(bf16x8*)&sB[(size_t)g * 8] = pk;
  }

  f32x4 acc[4][4];
#pragma unroll
  for (int m = 0; m < 4; ++m)
#pragma unroll
    for (int n = 0; n < 4; ++n) acc[m][n] = (f32x4){0.f, 0.f, 0.f, 0.f};

  for (int kb = 0; kb < 6; ++kb) {
    __syncthreads();                         // prev compute done (first: covers sB)
#pragma unroll
    for (int r = 0; r < 4; ++r) {            // stage A-chunk [tg 0..15][lane]
      int g = tid + 256 * r;
      int tg = g >> 6, qd = (g >> 4) & 3, l5 = g & 15;
      bf16x8 v = *(const bf16x8*)&XT[((size_t)b * T_ + t0 + tg * 16 + l5) * D_ +
                                     kb * 32 + qd * 8];
      *(bf16x8*)&sA[(size_t)g * 8] = v;
    }
    __syncthreads();
    bf16x8 bf[4];
#pragma unroll
    for (int n = 0; n < 4; ++n)
      bf[n] = *(const bf16x8*)&sB[(size_t)((kb * 4 + n) * 64 + lane) * 8];
#pragma unroll
    for (int m = 0; m < 4; ++m) {
      bf16x8 af = *(const bf16x8*)&sA[(size_t)((wv * 4 + m) * 64 + lane) * 8];
#pragma unroll
      for (int n = 0; n < 4; ++n)
        acc[m][n] = __builtin_amdgcn_mfma_f32_16x16x32_bf16(af, bf[n], acc[m][n], 0, 0, 0);
    }
  }
  __syncthreads();                           // before epilogue overlay

  // epilogue: per-wave LDS transpose, f32 coalesced stores
  float bs[4];
#pragma unroll
  for (int n = 0; n < 4; ++n) bs[n] = bias[o0 + n * 16 + l15];
  float* se = sE + wv * 1088;                // [16 t][68]
#pragma unroll
  for (int m = 0; m < 4; ++m) {
#pragma unroll
    for (int n = 0; n < 4; ++n)
#pragma unroll
      for (int r = 0; r < 4; ++r)
        se[(quad * 4 + r) * 68 + n * 16 + l15] = (acc[m][n][r] + bs[n]) * outscale;
    // same-wave DS in-order: no barrier needed
#pragma unroll
    for (int oo = 0; oo < 16; ++oo) {
      int ol = oo * 4 + quad;
      Y[((size_t)b * D_ + o0 + ol) * T_ + t0 + wv * 64 + m * 16 + l15] =
          se[l15 * 68 + ol];
    }
  }
}

// ---------------- packed-fragment bf16-MFMA flash attention ----------------
// Block = (b, h, 64 t); wave owns 16 t. Chunk = 64 s.
// LDS 28672 B: kt 12288 | vt 12288 | sP 4096; qt overlays kt (prologue),
// sO (epilogue, 26112 B) overlays everything. 4 blocks/CU.
__global__ __launch_bounds__(256, 4) void attn_kernel(
    const float* __restrict__ qws, const bf16* __restrict__ ktg,
    const bf16* __restrict__ vtg, bf16* __restrict__ owsT) {
  __shared__ __align__(16) char smem[28672];
  bf16* kt = (bf16*)smem;                    // [3 kb][4 n][64][8] = 12288
  bf16* vt = (bf16*)(smem + 12288);          // [2 kb][6 n][64][8] = 12288
  bf16* sP = (bf16*)(smem + 24576);          // [4 wv][64][8]      =  4096
  bf16* qt = (bf16*)smem;                    // prologue overlay (12288)
  float* sO = (float*)smem;                  // epilogue overlay [96][68] f32 = 26112

  const int tid = threadIdx.x;
  const int t0 = blockIdx.x * 64, h = blockIdx.y, b = blockIdx.z;
  const int lane = tid & 63, wv = tid >> 6;
  const int quad = lane >> 4, l15 = lane & 15;

  const bf16* kb_g = ktg + (size_t)h * SP * DK;
  const bf16* vb_g = vtg + (size_t)h * DK * SP;

  // per-thread chunk-invariant staging source addresses
  const bf16* kp[3];
  const bf16* vp[3];
#pragma unroll
  for (int r = 0; r < 3; ++r) {
    int g = tid + 256 * r;
    {
      int kb = g >> 8, n = (g >> 6) & 3, qd = (g >> 4) & 3, l5 = g & 15;
      kp[r] = kb_g + (size_t)(n * 16 + l5) * DK + kb * 32 + qd * 8;
    }
    {
      int gg = g >> 6;
      int kb = gg / 6, n = gg % 6, qd = (g >> 4) & 3, l5 = g & 15;
      vp[r] = vb_g + (size_t)(n * 16 + l5) * SP + kb * 32 + qd * 8;
    }
  }

  // prefetch chunk 0 K/V into registers (latency overlaps Q staging below)
  bf16x8 kreg[3], vreg[3];
#pragma unroll
  for (int r = 0; r < 3; ++r) {
    kreg[r] = *(const bf16x8*)kp[r];
    vreg[r] = *(const bf16x8*)vp[r];
  }

  // stage Q once (q carries SCALE*LOG2E folded by proj): f32 [i][t] -> packed A-frags
#pragma unroll
  for (int r = 0; r < 24; ++r) {
    int idx = tid + 256 * r;                 // 96 i x 64 t
    int i = idx >> 6, t = idx & 63;
    float v = qws[((size_t)(b * D_ + h * DK + i)) * T_ + t0 + t];
    int kb = i >> 5, qd = (i >> 3) & 3, j = i & 7, w = t >> 4, l5 = t & 15;
    qt[(size_t)(((kb * 4 + w) * 64 + qd * 16 + l5)) * 8 + j] = (bf16)v;
  }
  __syncthreads();
  bf16x8 qf[3];                              // Q fragments hoisted to registers
#pragma unroll
  for (int kb = 0; kb < 3; ++kb)
    qf[kb] = *(const bf16x8*)&qt[(size_t)((kb * 4 + wv) * 64 + lane) * 8];

  f32x4 oacc[6];
#pragma unroll
  for (int n = 0; n < 6; ++n) oacc[n] = (f32x4){0.f, 0.f, 0.f, 0.f};
  float m_run[4] = {-1e30f, -1e30f, -1e30f, -1e30f};
  float l_run[4] = {0.f, 0.f, 0.f, 0.f};

  for (int ch = 0; ch < 16; ++ch) {
    __syncthreads();                         // (A) prev readers (incl qf) done
#pragma unroll
    for (int r = 0; r < 3; ++r) {            // regs -> LDS (vmcnt wait compiler-inserted)
      *(bf16x8*)&kt[(size_t)(tid + 256 * r) * 8] = kreg[r];
      *(bf16x8*)&vt[(size_t)(tid + 256 * r) * 8] = vreg[r];
    }
    __syncthreads();                         // (B) staged
    if (ch < 15) {                           // issue next chunk's loads; hidden under compute
      const size_t ko = (size_t)(ch + 1) * 64 * DK;
      const size_t vo = (size_t)(ch + 1) * 64;
#pragma unroll
      for (int r = 0; r < 3; ++r) {
        kreg[r] = *(const bf16x8*)(kp[r] + ko);
        vreg[r] = *(const bf16x8*)(vp[r] + vo);
      }
    }

    // ---- QK^T (Q from registers, K frag reads lane-contiguous) ----
    f32x4 sacc[4];
#pragma unroll
    for (int n = 0; n < 4; ++n) sacc[n] = (f32x4){0.f, 0.f, 0.f, 0.f};
#pragma unroll
    for (int kb = 0; kb < 3; ++kb) {
#pragma unroll
      for (int n = 0; n < 4; ++n) {
        bf16x8 bfm = *(const bf16x8*)&kt[(size_t)((kb * 4 + n) * 64 + lane) * 8];
        sacc[n] = __builtin_amdgcn_mfma_f32_16x16x32_bf16(qf[kb], bfm, sacc[n], 0, 0, 0);
      }
    }
    if (ch == 15) {                          // mask s >= 1000 (s-local >= 40)
#pragma unroll
      for (int r = 0; r < 4; ++r) {
        if (l15 >= 8) sacc[2][r] = -1e30f;
        sacc[3][r] = -1e30f;
      }
    }

    // ---- register online softmax, log2 domain (row = 16 lanes of this quad) ----
    float mc[4];
#pragma unroll
    for (int r = 0; r < 4; ++r) {
      float m0 = fmaxf(fmaxf(sacc[0][r], sacc[1][r]), fmaxf(sacc[2][r], sacc[3][r]));
      m0 = fmaxf(m0, __shfl_xor(m0, 1, 64));
      m0 = fmaxf(m0, __shfl_xor(m0, 2, 64));
      m0 = fmaxf(m0, __shfl_xor(m0, 4, 64));
      m0 = fmaxf(m0, __shfl_xor(m0, 8, 64));
      mc[r] = m0;
    }
    // defer-max (T13): skip rescale when max growth <= 8 (P bounded by 2^8, bf16-safe)
    bool keep = (mc[0] - m_run[0] <= 8.f) && (mc[1] - m_run[1] <= 8.f) &&
                (mc[2] - m_run[2] <= 8.f) && (mc[3] - m_run[3] <= 8.f);
    if (!__all(keep)) {
#pragma unroll
      for (int r = 0; r < 4; ++r) {
        float mn = fmaxf(m_run[r], mc[r]);
        float al = exp2f(m_run[r] - mn);     // first chunk: exp2(-inf) = 0
        m_run[r] = mn;
        l_run[r] *= al;
#pragma unroll
        for (int n = 0; n < 6; ++n) oacc[n][r] *= al;
      }
    }
    float pr[4][4];                          // [n][r]
#pragma unroll
    for (int r = 0; r < 4; ++r) {
      float ls = 0.f;
#pragma unroll
      for (int n = 0; n < 4; ++n) { pr[n][r] = exp2f(sacc[n][r] - m_run[r]); ls += pr[n][r]; }
      ls += __shfl_xor(ls, 1, 64);
      ls += __shfl_xor(ls, 2, 64);
      ls += __shfl_xor(ls, 4, 64);
      ls += __shfl_xor(ls, 8, 64);
      l_run[r] += ls;
    }

    // ---- P -> packed A-frags in LDS, split per kb (same-wave in-order, no barrier) ----
#pragma unroll
    for (int kb = 0; kb < 2; ++kb) {
#pragma unroll
      for (int nn = 0; nn < 2; ++nn) {
        int n = kb * 2 + nn;
        int qd2 = (nn << 1) | (l15 >> 3), j = l15 & 7;
#pragma unroll
        for (int r = 0; r < 4; ++r)
          sP[(size_t)((wv * 64 + qd2 * 16 + quad * 4 + r)) * 8 + j] = (bf16)pr[n][r];
      }
      bf16x8 pa = *(const bf16x8*)&sP[(size_t)(wv * 64 + lane) * 8];
#pragma unroll
      for (int n2 = 0; n2 < 6; ++n2) {
        bf16x8 vf = *(const bf16x8*)&vt[(size_t)((kb * 6 + n2) * 64 + lane) * 8];
        oacc[n2] = __builtin_amdgcn_mfma_f32_16x16x32_bf16(pa, vf, oacc[n2], 0, 0, 0);
      }
    }
  }

  // ---- epilogue: /l, LDS transpose, bf16 [b][t][c] out ----
  float inv[4];
#pragma unroll
  for (int r = 0; r < 4; ++r) inv[r] = 1.0f / l_run[r];
  __syncthreads();
#pragma unroll
  for (int n = 0; n < 6; ++n)
#pragma unroll
    for (int r = 0; r < 4; ++r)
      sO[(n * 16 + l15) * 68 + wv * 16 + quad * 4 + r] = oacc[n][r] * inv[r];
  __syncthreads();
#pragma unroll
  for (int r = 0; r < 24; ++r) {
    int idx = tid + 256 * r;                 // 64 t x 96 i, i fast (coalesced out)
    int t = idx / 96, i = idx % 96;
    owsT[((size_t)b * T_ + t0 + t) * D_ + h * DK + i] = (bf16)sO[i * 68 + t];
  }
}

extern "C" void kernel_launch(void* const* d_in, const int* in_sizes, int n_in,
                              void* d_out, int out_size, void* d_ws, size_t ws_size,
                              hipStream_t stream) {
  const float* z  = (const float*)d_in[0];
  const float* mb = (const float*)d_in[1];
  const float* Wq = (const float*)d_in[2];
  const float* bq = (const float*)d_in[3];
  const float* Wk = (const float*)d_in[4];
  const float* bk = (const float*)d_in[5];
  const float* Wv = (const float*)d_in[6];
  const float* bv = (const float*)d_in[7];
  const float* Wo = (const float*)d_in[8];
  const float* bo = (const float*)d_in[9];
  float* out = (float*)d_out;

  // ws: ktg | vtg | zT | owsT (bf16)  then qws (f32)
  bf16* ktg  = (bf16*)d_ws;
  bf16* vtg  = ktg + 2 * SP * DK;
  bf16* zT   = vtg + 2 * DK * SP;
  bf16* owsT = zT + (size_t)B_ * T_ * D_;
  float* qws = (float*)(owsT + (size_t)B_ * T_ * D_);

  kv_kernel  <<<dim3(SP / 256, D_),    256, 0, stream>>>(mb, Wk, bk, Wv, bv, ktg, vtg);
  zt_kernel  <<<dim3(T_ / 64, B_),     256, 0, stream>>>(z, zT);
  // fold log2e into Q so softmax runs in exp2 domain
  proj_kernel<<<dim3(T_ / 256, 3, B_), 256, 0, stream>>>(zT, Wq, bq, qws, SCALE * LOG2E);
  attn_kernel<<<dim3(T_ / 64, 2, B_),  256, 0, stream>>>(qws, ktg, vtg, owsT);
  proj_kernel<<<dim3(T_ / 256, 3, B_), 256, 0, stream>>>(owsT, Wo, bo, out, 1.0f);
}

// Round 2
// 300.015 us; speedup vs baseline: 1.1136x; 1.0025x over previous
//
#include <hip/hip_runtime.h>

// R7: occupancy + amortization attack on attn.
//  - Block = 128 t, 512 threads (8 waves x 16 t): staging/barriers per chunk amortized
//    over 2x waves; LDS = 32768 B (kt 12K | vt 12K | sP 8K) -> 4 blocks/CU; grid = 1024
//    blocks = exactly 4/CU, one clean round, up to 32 waves/CU.
//  - qws bf16 (proj templated on out dtype): halves Q write + attn Q read.
//  - sP granule XOR-swizzle (involution g^=(g>>2)&3 on write+read) kills the 4-way
//    bank conflict on P scalar writes.
//  - Keeps R6: reg K/V prefetch, Q frags in regs, exp2-domain softmax (log2e folded
//    into Q proj), defer-max THR=8, packed-fragment conflict-free b128 tiles.

typedef float  f32x4  __attribute__((ext_vector_type(4)));
typedef __bf16 bf16;
typedef __bf16 bf16x8 __attribute__((ext_vector_type(8)));

#define B_   16
#define D_   192
#define T_   4096
#define BANK 1000
#define SP   1024
#define DK   96
#define SCALE 0.10206207261596577f   // 1/sqrt(96)
#define LOG2E 1.4426950408889634f

// ---------------- K/V projection (tiny) ----------------
// ktg: [h][1024 s][96 i]   vtg: [h][96 i][1024 s]
__global__ __launch_bounds__(256) void kv_kernel(
    const float* __restrict__ mb, const float* __restrict__ Wk, const float* __restrict__ bk,
    const float* __restrict__ Wv, const float* __restrict__ bv,
    bf16* __restrict__ ktg, bf16* __restrict__ vtg) {
  int s = blockIdx.x * 256 + threadIdx.x;
  int o = blockIdx.y;
  int h = o / DK, i = o % DK;
  float ak = 0.f, av = 0.f;
  if (s < BANK) {
    ak = bk[o]; av = bv[o];
    for (int c = 0; c < D_; ++c) {
      float m = mb[c * BANK + s];
      ak += Wk[o * D_ + c] * m;
      av += Wv[o * D_ + c] * m;
    }
  }
  ktg[(size_t)(h * SP + s) * DK + i] = (bf16)ak;
  vtg[(size_t)(h * DK + i) * SP + s] = (bf16)av;
}

// ---------------- z transpose: z f32 [b][c][t] -> zT bf16 [b][t][c] ----------------
__global__ __launch_bounds__(256) void zt_kernel(const float* __restrict__ z,
                                                 bf16* __restrict__ zT) {
  __shared__ __align__(16) bf16 sT[64 * 200];
  const int tid = threadIdx.x;
  const int t0 = blockIdx.x * 64, b = blockIdx.y;
#pragma unroll
  for (int it = 0; it < 48; ++it) {          // 192c x 64t, coalesced along t
    int e = tid + 256 * it;
    int c = e >> 6, tl = e & 63;
    sT[tl * 200 + c] = (bf16)z[((size_t)b * D_ + c) * T_ + t0 + tl];
  }
  __syncthreads();
#pragma unroll
  for (int it = 0; it < 6; ++it) {           // 1536 granules of 8 bf16
    int g = tid + 256 * it;
    int tl = g / 24, c8 = (g % 24) * 8;
    bf16x8 v = *(const bf16x8*)&sT[tl * 200 + c8];
    *(bf16x8*)&zT[((size_t)b * T_ + t0 + tl) * D_ + c8] = v;
  }
}

// ---------------- MFMA projection: Y[b][o][t] = (W · X + bias) * outscale ----------------
// XT bf16 [b][t][192 c]; W f32 [o][c]; Y (f32 or bf16) [b][o][t].
template <typename OT>
__global__ __launch_bounds__(256) void proj_kernel(
    const bf16* __restrict__ XT, const float* __restrict__ W,
    const float* __restrict__ bias, OT* __restrict__ Y, float outscale) {
  __shared__ __align__(16) char smem[40960];
  bf16* sA = (bf16*)smem;                    // per-chunk [16 tg][64 lane][8] = 16384 B
  bf16* sB = (bf16*)(smem + 16384);          // [6 kb][4 nt][64 lane][8]     = 24576 B
  float* sE = (float*)smem;                  // epilogue overlay: 4 waves x [16][68] f32

  const int tid = threadIdx.x;
  const int t0 = blockIdx.x * 256, o0 = blockIdx.y * 64, b = blockIdx.z;
  const int lane = tid & 63, wv = tid >> 6;
  const int quad = lane >> 4, l15 = lane & 15;

#pragma unroll
  for (int r = 0; r < 6; ++r) {
    int g = tid + 256 * r;                   // [kb][nt][lane]
    int kb = g >> 8, nt = (g >> 6) & 3, qd = (g >> 4) & 3, l5 = g & 15;
    const float* wp = &W[(o0 + nt * 16 + l5) * D_ + kb * 32 + qd * 8];
    f32x4 wa = *(const f32x4*)wp, wb = *(const f32x4*)(wp + 4);
    bf16x8 pk;
#pragma unroll
    for (int u = 0; u < 4; ++u) { pk[u] = (bf16)wa[u]; pk[4 + u] = (bf16)wb[u]; }
    *(bf16x8*)&sB[(size_t)g * 8] = pk;
  }

  f32x4 acc[4][4];
#pragma unroll
  for (int m = 0; m < 4; ++m)
#pragma unroll
    for (int n = 0; n < 4; ++n) acc[m][n] = (f32x4){0.f, 0.f, 0.f, 0.f};

  for (int kb = 0; kb < 6; ++kb) {
    __syncthreads();
#pragma unroll
    for (int r = 0; r < 4; ++r) {
      int g = tid + 256 * r;
      int tg = g >> 6, qd = (g >> 4) & 3, l5 = g & 15;
      bf16x8 v = *(const bf16x8*)&XT[((size_t)b * T_ + t0 + tg * 16 + l5) * D_ +
                                     kb * 32 + qd * 8];
      *(bf16x8*)&sA[(size_t)g * 8] = v;
    }
    __syncthreads();
    bf16x8 bf[4];
#pragma unroll
    for (int n = 0; n < 4; ++n)
      bf[n] = *(const bf16x8*)&sB[(size_t)((kb * 4 + n) * 64 + lane) * 8];
#pragma unroll
    for (int m = 0; m < 4; ++m) {
      bf16x8 af = *(const bf16x8*)&sA[(size_t)((wv * 4 + m) * 64 + lane) * 8];
#pragma unroll
      for (int n = 0; n < 4; ++n)
        acc[m][n] = __builtin_amdgcn_mfma_f32_16x16x32_bf16(af, bf[n], acc[m][n], 0, 0, 0);
    }
  }
  __syncthreads();

  float bs[4];
#pragma unroll
  for (int n = 0; n < 4; ++n) bs[n] = bias[o0 + n * 16 + l15];
  float* se = sE + wv * 1088;                // [16 t][68]
#pragma unroll
  for (int m = 0; m < 4; ++m) {
#pragma unroll
    for (int n = 0; n < 4; ++n)
#pragma unroll
      for (int r = 0; r < 4; ++r)
        se[(quad * 4 + r) * 68 + n * 16 + l15] = (acc[m][n][r] + bs[n]) * outscale;
#pragma unroll
    for (int oo = 0; oo < 16; ++oo) {        // same-wave DS in-order: no barrier
      int ol = oo * 4 + quad;
      Y[((size_t)b * D_ + o0 + ol) * T_ + t0 + wv * 64 + m * 16 + l15] =
          (OT)se[l15 * 68 + ol];
    }
  }
}

// ---------------- packed-fragment bf16-MFMA flash attention ----------------
// Block = (b, h, 128 t); 8 waves x 16 t. Chunk = 64 s.
// LDS 32768 B: kt 12288 | vt 12288 | sP 8192 (granule-swizzled).
// qt (24576) overlays kt+vt in prologue; per-wave bf16 [96][17] epilogue overlay.
__global__ __launch_bounds__(512) void attn_kernel(
    const bf16* __restrict__ qws, const bf16* __restrict__ ktg,
    const bf16* __restrict__ vtg, bf16* __restrict__ owsT) {
  __shared__ __align__(16) char smem[32768];
  bf16* kt = (bf16*)smem;                    // [3 kb][4 n][64][8] = 12288
  bf16* vt = (bf16*)(smem + 12288);          // [2 kb][6 n][64][8] = 12288
  bf16* sP = (bf16*)(smem + 24576);          // [8 wv][64][8]      =  8192
  bf16* qt = (bf16*)smem;                    // prologue overlay (24576)

  const int tid = threadIdx.x;
  const int t0 = blockIdx.x * 128, h = blockIdx.y, b = blockIdx.z;
  const int lane = tid & 63, wv = tid >> 6;
  const int quad = lane >> 4, l15 = lane & 15;

  const bf16* kb_g = ktg + (size_t)h * SP * DK;
  const bf16* vb_g = vtg + (size_t)h * DK * SP;

  // combined K|V staging: 1536 granules, 3 per thread, per-wave-uniform K/V split
  const bf16* sp_ptr[3];
  int sp_str[3];
#pragma unroll
  for (int r = 0; r < 3; ++r) {
    int g = tid + 512 * r;
    if (g < 768) {                           // K granule
      int kb = g >> 8, n = (g >> 6) & 3, qd = (g >> 4) & 3, l5 = g & 15;
      sp_ptr[r] = kb_g + (size_t)(n * 16 + l5) * DK + kb * 32 + qd * 8;
      sp_str[r] = 64 * DK;
    } else {                                 // V granule
      int gv = g - 768, blk = gv >> 6;
      int kbv = blk / 6, n = blk % 6, qd = (gv >> 4) & 3, l5 = gv & 15;
      sp_ptr[r] = vb_g + (size_t)(n * 16 + l5) * SP + kbv * 32 + qd * 8;
      sp_str[r] = 64;
    }
  }
  bf16x8 kreg[3];
#pragma unroll
  for (int r = 0; r < 3; ++r) kreg[r] = *(const bf16x8*)sp_ptr[r];

  // stage Q (bf16, SCALE*LOG2E pre-folded) -> packed A-frags in qt overlay
#pragma unroll
  for (int r = 0; r < 3; ++r) {
    int g8 = tid + 512 * r;                  // 96 i x 16 t8-groups
    int i = g8 >> 4, t8 = (g8 & 15) * 8;
    bf16x8 v = *(const bf16x8*)&qws[((size_t)(b * D_ + h * DK + i)) * T_ + t0 + t8];
    int kb = i >> 5, qd = (i >> 3) & 3, j = i & 7;
#pragma unroll
    for (int tt = 0; tt < 8; ++tt) {
      int t = t8 + tt;
      qt[(size_t)((kb * 8 + (t >> 4)) * 64 + qd * 16 + (t & 15)) * 8 + j] = v[tt];
    }
  }
  __syncthreads();
  bf16x8 qf[3];
#pragma unroll
  for (int kb = 0; kb < 3; ++kb)
    qf[kb] = *(const bf16x8*)&qt[(size_t)((kb * 8 + wv) * 64 + lane) * 8];

  f32x4 oacc[6];
#pragma unroll
  for (int n = 0; n < 6; ++n) oacc[n] = (f32x4){0.f, 0.f, 0.f, 0.f};
  float m_run[4] = {-1e30f, -1e30f, -1e30f, -1e30f};
  float l_run[4] = {0.f, 0.f, 0.f, 0.f};

  for (int ch = 0; ch < 16; ++ch) {
    __syncthreads();                         // (A) prev readers (incl qf) done
#pragma unroll
    for (int r = 0; r < 3; ++r)              // regs -> LDS, lane-linear (conflict-free)
      *(bf16x8*)(smem + (size_t)(tid + 512 * r) * 16) = kreg[r];
    __syncthreads();                         // (B) staged
    if (ch < 15) {                           // issue next chunk's loads under compute
#pragma unroll
      for (int r = 0; r < 3; ++r) {
        sp_ptr[r] += sp_str[r];
        kreg[r] = *(const bf16x8*)sp_ptr[r];
      }
    }

    // ---- QK^T (Q in regs, K frag reads lane-contiguous) ----
    f32x4 sacc[4];
#pragma unroll
    for (int n = 0; n < 4; ++n) sacc[n] = (f32x4){0.f, 0.f, 0.f, 0.f};
#pragma unroll
    for (int kb = 0; kb < 3; ++kb) {
#pragma unroll
      for (int n = 0; n < 4; ++n) {
        bf16x8 bfm = *(const bf16x8*)&kt[(size_t)((kb * 4 + n) * 64 + lane) * 8];
        sacc[n] = __builtin_amdgcn_mfma_f32_16x16x32_bf16(qf[kb], bfm, sacc[n], 0, 0, 0);
      }
    }
    if (ch == 15) {                          // mask s >= 1000 (s-local >= 40)
#pragma unroll
      for (int r = 0; r < 4; ++r) {
        if (l15 >= 8) sacc[2][r] = -1e30f;
        sacc[3][r] = -1e30f;
      }
    }

    // ---- register online softmax, exp2 domain ----
    float mc[4];
#pragma unroll
    for (int r = 0; r < 4; ++r) {
      float m0 = fmaxf(fmaxf(sacc[0][r], sacc[1][r]), fmaxf(sacc[2][r], sacc[3][r]));
      m0 = fmaxf(m0, __shfl_xor(m0, 1, 64));
      m0 = fmaxf(m0, __shfl_xor(m0, 2, 64));
      m0 = fmaxf(m0, __shfl_xor(m0, 4, 64));
      m0 = fmaxf(m0, __shfl_xor(m0, 8, 64));
      mc[r] = m0;
    }
    bool keep = (mc[0] - m_run[0] <= 8.f) && (mc[1] - m_run[1] <= 8.f) &&
                (mc[2] - m_run[2] <= 8.f) && (mc[3] - m_run[3] <= 8.f);
    if (!__all(keep)) {                      // defer-max (T13)
#pragma unroll
      for (int r = 0; r < 4; ++r) {
        float mn = fmaxf(m_run[r], mc[r]);
        float al = exp2f(m_run[r] - mn);
        m_run[r] = mn;
        l_run[r] *= al;
#pragma unroll
        for (int n = 0; n < 6; ++n) oacc[n][r] *= al;
      }
    }
    float pr[4][4];                          // [n][r]
#pragma unroll
    for (int r = 0; r < 4; ++r) {
      float ls = 0.f;
#pragma unroll
      for (int n = 0; n < 4; ++n) { pr[n][r] = exp2f(sacc[n][r] - m_run[r]); ls += pr[n][r]; }
      ls += __shfl_xor(ls, 1, 64);
      ls += __shfl_xor(ls, 2, 64);
      ls += __shfl_xor(ls, 4, 64);
      ls += __shfl_xor(ls, 8, 64);
      l_run[r] += ls;
    }

    // ---- P -> swizzled A-frags in LDS (same-wave in-order, no barrier), then PV ----
#pragma unroll
    for (int kb = 0; kb < 2; ++kb) {
#pragma unroll
      for (int nn = 0; nn < 2; ++nn) {
        int n = kb * 2 + nn;
        int qd2 = (nn << 1) | (l15 >> 3), j = l15 & 7;
#pragma unroll
        for (int r = 0; r < 4; ++r)          // granule swizzle: r -> r^quad
          sP[(size_t)(wv * 64 + qd2 * 16 + quad * 4 + (r ^ quad)) * 8 + j] =
              (bf16)pr[n][r];
      }
      bf16x8 pa = *(const bf16x8*)&sP[(size_t)(wv * 64 + (lane ^ ((lane >> 2) & 3))) * 8];
#pragma unroll
      for (int n2 = 0; n2 < 6; ++n2) {
        bf16x8 vf = *(const bf16x8*)&vt[(size_t)((kb * 6 + n2) * 64 + lane) * 8];
        oacc[n2] = __builtin_amdgcn_mfma_f32_16x16x32_bf16(pa, vf, oacc[n2], 0, 0, 0);
      }
    }
  }

  // ---- epilogue: /l, per-wave bf16 LDS transpose [96][17], coalesced bf16 out ----
  float inv[4];
#pragma unroll
  for (int r = 0; r < 4; ++r) inv[r] = 1.0f / l_run[r];
  __syncthreads();                           // all waves done with kt/vt/sP
  bf16* sOw = (bf16*)smem + wv * (96 * 17);
#pragma unroll
  for (int n2 = 0; n2 < 6; ++n2)
#pragma unroll
    for (int r = 0; r < 4; ++r)
      sOw[(n2 * 16 + l15) * 17 + quad * 4 + r] = (bf16)(oacc[n2][r] * inv[r]);
  // same-wave DS in-order: safe to read back without barrier
#pragma unroll
  for (int r2 = 0; r2 < 24; ++r2) {
    int g = r2 * 64 + lane;                  // 16 t x 96 i, i fast (coalesced out)
    int tl = g / 96, i = g % 96;
    owsT[((size_t)b * T_ + t0 + wv * 16 + tl) * D_ + h * DK + i] = sOw[i * 17 + tl];
  }
}

extern "C" void kernel_launch(void* const* d_in, const int* in_sizes, int n_in,
                              void* d_out, int out_size, void* d_ws, size_t ws_size,
                              hipStream_t stream) {
  const float* z  = (const float*)d_in[0];
  const float* mb = (const float*)d_in[1];
  const float* Wq = (const float*)d_in[2];
  const float* bq = (const float*)d_in[3];
  const float* Wk = (const float*)d_in[4];
  const float* bk = (const float*)d_in[5];
  const float* Wv = (const float*)d_in[6];
  const float* bv = (const float*)d_in[7];
  const float* Wo = (const float*)d_in[8];
  const float* bo = (const float*)d_in[9];
  float* out = (float*)d_out;

  // ws: ktg | vtg | zT | owsT | qws (all bf16)
  bf16* ktg  = (bf16*)d_ws;
  bf16* vtg  = ktg + 2 * SP * DK;
  bf16* zT   = vtg + 2 * DK * SP;
  bf16* owsT = zT + (size_t)B_ * T_ * D_;
  bf16* qws  = owsT + (size_t)B_ * T_ * D_;

  kv_kernel        <<<dim3(SP / 256, D_),    256, 0, stream>>>(mb, Wk, bk, Wv, bv, ktg, vtg);
  zt_kernel        <<<dim3(T_ / 64, B_),     256, 0, stream>>>(z, zT);
  // fold log2e into Q so softmax runs in exp2 domain; q stored bf16
  proj_kernel<bf16><<<dim3(T_ / 256, 3, B_), 256, 0, stream>>>(zT, Wq, bq, qws, SCALE * LOG2E);
  attn_kernel      <<<dim3(T_ / 128, 2, B_), 512, 0, stream>>>(qws, ktg, vtg, owsT);
  proj_kernel<float><<<dim3(T_ / 256, 3, B_), 256, 0, stream>>>(owsT, Wo, bo, out, 1.0f);
}

// Round 3
// 282.842 us; speedup vs baseline: 1.1812x; 1.0607x over previous
//
#include <hip/hip_runtime.h>

// R8: latency + bank-conflict fixes, structure otherwise preserved.
//  - proj_kernel: T14 register prefetch of A-chunks (global latency off the critical
//    path; mirrors the proven attn staging pattern).
//  - attn: proper LDS granule swizzles. sP: sigma(g)=g^((g>>3)&7) -> P scalar writes
//    spread 64 lanes over 32 banks (2/bank, same-dword). qt prologue: sigma(G)=
//    G^((G>>6)&7) -> 24 prologue scatter writes drop from 16-32-way to ~4-way;
//    qf read stays a within-16 permutation (conflict-free b128).
//  - kv + zt merged into one dispatch (pre_kernel) -> one less serialization boundary.
//  - Keeps R7: 512-thr attn blocks, reg K/V prefetch, Q frags in regs, exp2-domain
//    softmax, defer-max THR=8, bf16 qws.

typedef float  f32x4  __attribute__((ext_vector_type(4)));
typedef __bf16 bf16;
typedef __bf16 bf16x8 __attribute__((ext_vector_type(8)));

#define B_   16
#define D_   192
#define T_   4096
#define BANK 1000
#define SP   1024
#define DK   96
#define SCALE 0.10206207261596577f   // 1/sqrt(96)
#define LOG2E 1.4426950408889634f

// ---------------- fused pre-work: zt (y<16) | kv (y>=16) ----------------
__global__ __launch_bounds__(256) void pre_kernel(
    const float* __restrict__ z, bf16* __restrict__ zT,
    const float* __restrict__ mb,
    const float* __restrict__ Wk, const float* __restrict__ bk,
    const float* __restrict__ Wv, const float* __restrict__ bv,
    bf16* __restrict__ ktg, bf16* __restrict__ vtg) {
  __shared__ __align__(16) bf16 sT[64 * 200];
  const int tid = threadIdx.x;
  if (blockIdx.y < 16) {
    // z transpose: z f32 [b][c][t] -> zT bf16 [b][t][c]
    const int t0 = blockIdx.x * 64, b = blockIdx.y;
#pragma unroll
    for (int it = 0; it < 48; ++it) {        // 192c x 64t, coalesced along t
      int e = tid + 256 * it;
      int c = e >> 6, tl = e & 63;
      sT[tl * 200 + c] = (bf16)z[((size_t)b * D_ + c) * T_ + t0 + tl];
    }
    __syncthreads();
#pragma unroll
    for (int it = 0; it < 6; ++it) {         // 1536 granules of 8 bf16
      int g = tid + 256 * it;
      int tl = g / 24, c8 = (g % 24) * 8;
      bf16x8 v = *(const bf16x8*)&sT[tl * 200 + c8];
      *(bf16x8*)&zT[((size_t)b * T_ + t0 + tl) * D_ + c8] = v;
    }
  } else {
    // K/V projection: ktg [h][1024 s][96 i], vtg [h][96 i][1024 s]
    int idx = (blockIdx.y - 16) * 64 + blockIdx.x;   // 0..767
    int s = (idx & 3) * 256 + tid;
    int o = idx >> 2;
    int h = o / DK, i = o % DK;
    float ak = 0.f, av = 0.f;
    if (s < BANK) {
      ak = bk[o]; av = bv[o];
      for (int c = 0; c < D_; ++c) {
        float m = mb[c * BANK + s];
        ak += Wk[o * D_ + c] * m;
        av += Wv[o * D_ + c] * m;
      }
    }
    ktg[(size_t)(h * SP + s) * DK + i] = (bf16)ak;
    vtg[(size_t)(h * DK + i) * SP + s] = (bf16)av;
  }
}

// ---------------- MFMA projection: Y[b][o][t] = (W · X + bias) * outscale ----------------
// XT bf16 [b][t][192 c]; W f32 [o][c]; Y (f32 or bf16) [b][o][t].
// T14: A-chunk register prefetch; per chunk {bar; regs->LDS; bar; issue kb+1; MFMA}.
template <typename OT>
__global__ __launch_bounds__(256) void proj_kernel(
    const bf16* __restrict__ XT, const float* __restrict__ W,
    const float* __restrict__ bias, OT* __restrict__ Y, float outscale) {
  __shared__ __align__(16) char smem[40960];
  bf16* sA = (bf16*)smem;                    // per-chunk [16 tg][64 lane][8] = 16384 B
  bf16* sB = (bf16*)(smem + 16384);          // [6 kb][4 nt][64 lane][8]     = 24576 B
  float* sE = (float*)smem;                  // epilogue overlay: 4 waves x [16][68] f32

  const int tid = threadIdx.x;
  const int t0 = blockIdx.x * 256, o0 = blockIdx.y * 64, b = blockIdx.z;
  const int lane = tid & 63, wv = tid >> 6;
  const int quad = lane >> 4, l15 = lane & 15;

  // A prefetch: chunk-invariant per-thread base (kb advances by +32 c)
  const bf16* ap[4];
#pragma unroll
  for (int r = 0; r < 4; ++r) {
    int g = tid + 256 * r;
    int tg = g >> 6, qd = (g >> 4) & 3, l5 = g & 15;
    ap[r] = &XT[((size_t)b * T_ + t0 + tg * 16 + l5) * D_ + qd * 8];
  }
  bf16x8 areg[4];
#pragma unroll
  for (int r = 0; r < 4; ++r) areg[r] = *(const bf16x8*)ap[r];

  // stage W (whole 64o x 192c) as packed B-frags, f32 -> bf16
#pragma unroll
  for (int r = 0; r < 6; ++r) {
    int g = tid + 256 * r;                   // [kb][nt][lane]
    int kb = g >> 8, nt = (g >> 6) & 3, qd = (g >> 4) & 3, l5 = g & 15;
    const float* wp = &W[(o0 + nt * 16 + l5) * D_ + kb * 32 + qd * 8];
    f32x4 wa = *(const f32x4*)wp, wb = *(const f32x4*)(wp + 4);
    bf16x8 pk;
#pragma unroll
    for (int u = 0; u < 4; ++u) { pk[u] = (bf16)wa[u]; pk[4 + u] = (bf16)wb[u]; }
    *(bf16x8*)&sB[(size_t)g * 8] = pk;
  }

  f32x4 acc[4][4];
#pragma unroll
  for (int m = 0; m < 4; ++m)
#pragma unroll
    for (int n = 0; n < 4; ++n) acc[m][n] = (f32x4){0.f, 0.f, 0.f, 0.f};

  for (int kb = 0; kb < 6; ++kb) {
    __syncthreads();                         // (A) prev compute done (first: covers sB)
#pragma unroll
    for (int r = 0; r < 4; ++r)              // regs -> LDS, lane-linear
      *(bf16x8*)&sA[(size_t)(tid + 256 * r) * 8] = areg[r];
    __syncthreads();                         // (B) staged
    if (kb < 5) {                            // issue next chunk's loads under compute
#pragma unroll
      for (int r = 0; r < 4; ++r)
        areg[r] = *(const bf16x8*)(ap[r] + (kb + 1) * 32);
    }
    bf16x8 bf[4];
#pragma unroll
    for (int n = 0; n < 4; ++n)
      bf[n] = *(const bf16x8*)&sB[(size_t)((kb * 4 + n) * 64 + lane) * 8];
#pragma unroll
    for (int m = 0; m < 4; ++m) {
      bf16x8 af = *(const bf16x8*)&sA[(size_t)((wv * 4 + m) * 64 + lane) * 8];
#pragma unroll
      for (int n = 0; n < 4; ++n)
        acc[m][n] = __builtin_amdgcn_mfma_f32_16x16x32_bf16(af, bf[n], acc[m][n], 0, 0, 0);
    }
  }
  __syncthreads();                           // before epilogue overlay

  float bs[4];
#pragma unroll
  for (int n = 0; n < 4; ++n) bs[n] = bias[o0 + n * 16 + l15];
  float* se = sE + wv * 1088;                // [16 t][68]
#pragma unroll
  for (int m = 0; m < 4; ++m) {
#pragma unroll
    for (int n = 0; n < 4; ++n)
#pragma unroll
      for (int r = 0; r < 4; ++r)
        se[(quad * 4 + r) * 68 + n * 16 + l15] = (acc[m][n][r] + bs[n]) * outscale;
#pragma unroll
    for (int oo = 0; oo < 16; ++oo) {        // same-wave DS in-order: no barrier
      int ol = oo * 4 + quad;
      Y[((size_t)b * D_ + o0 + ol) * T_ + t0 + wv * 64 + m * 16 + l15] =
          (OT)se[l15 * 68 + ol];
    }
  }
}

// ---------------- packed-fragment bf16-MFMA flash attention ----------------
// Block = (b, h, 128 t); 8 waves x 16 t. Chunk = 64 s.
// LDS 32768 B: kt 12288 | vt 12288 | sP 8192 (sigma-swizzled granules).
// qt (24576, sigma-swizzled) overlays kt+vt in prologue.
__global__ __launch_bounds__(512) void attn_kernel(
    const bf16* __restrict__ qws, const bf16* __restrict__ ktg,
    const bf16* __restrict__ vtg, bf16* __restrict__ owsT) {
  __shared__ __align__(16) char smem[32768];
  bf16* kt = (bf16*)smem;                    // [3 kb][4 n][64][8] = 12288
  bf16* vt = (bf16*)(smem + 12288);          // [2 kb][6 n][64][8] = 12288
  bf16* sP = (bf16*)(smem + 24576);          // [8 wv][64][8]      =  8192
  bf16* qt = (bf16*)smem;                    // prologue overlay (24576)

  const int tid = threadIdx.x;
  const int t0 = blockIdx.x * 128, h = blockIdx.y, b = blockIdx.z;
  const int lane = tid & 63, wv = tid >> 6;
  const int quad = lane >> 4, l15 = lane & 15;

  const bf16* kb_g = ktg + (size_t)h * SP * DK;
  const bf16* vb_g = vtg + (size_t)h * DK * SP;

  // combined K|V staging: 1536 granules, 3 per thread, per-wave-uniform K/V split
  const bf16* sp_ptr[3];
  int sp_str[3];
#pragma unroll
  for (int r = 0; r < 3; ++r) {
    int g = tid + 512 * r;
    if (g < 768) {                           // K granule
      int kb = g >> 8, n = (g >> 6) & 3, qd = (g >> 4) & 3, l5 = g & 15;
      sp_ptr[r] = kb_g + (size_t)(n * 16 + l5) * DK + kb * 32 + qd * 8;
      sp_str[r] = 64 * DK;
    } else {                                 // V granule
      int gv = g - 768, blk = gv >> 6;
      int kbv = blk / 6, n = blk % 6, qd = (gv >> 4) & 3, l5 = gv & 15;
      sp_ptr[r] = vb_g + (size_t)(n * 16 + l5) * SP + kbv * 32 + qd * 8;
      sp_str[r] = 64;
    }
  }
  bf16x8 kreg[3];
#pragma unroll
  for (int r = 0; r < 3; ++r) kreg[r] = *(const bf16x8*)sp_ptr[r];

  // stage Q (bf16, SCALE*LOG2E pre-folded) -> sigma-swizzled A-frags in qt overlay
#pragma unroll
  for (int r = 0; r < 3; ++r) {
    int g8 = tid + 512 * r;                  // 96 i x 16 t8-groups
    int i = g8 >> 4, t8 = (g8 & 15) * 8;
    bf16x8 v = *(const bf16x8*)&qws[((size_t)(b * D_ + h * DK + i)) * T_ + t0 + t8];
    int kb = i >> 5, qd = (i >> 3) & 3, j = i & 7;
#pragma unroll
    for (int tt = 0; tt < 8; ++tt) {
      int t = t8 + tt;
      int G = (kb * 8 + (t >> 4)) * 64 + qd * 16 + (t & 15);
      int Gs = G ^ ((G >> 6) & 7);           // bank-spread swizzle
      qt[(size_t)Gs * 8 + j] = v[tt];
    }
  }
  __syncthreads();
  bf16x8 qf[3];
#pragma unroll
  for (int kb = 0; kb < 3; ++kb) {
    int G = (kb * 8 + wv) * 64 + lane;
    int Gs = G ^ ((G >> 6) & 7);
    qf[kb] = *(const bf16x8*)&qt[(size_t)Gs * 8];
  }

  f32x4 oacc[6];
#pragma unroll
  for (int n = 0; n < 6; ++n) oacc[n] = (f32x4){0.f, 0.f, 0.f, 0.f};
  float m_run[4] = {-1e30f, -1e30f, -1e30f, -1e30f};
  float l_run[4] = {0.f, 0.f, 0.f, 0.f};

  for (int ch = 0; ch < 16; ++ch) {
    __syncthreads();                         // (A) prev readers (incl qf) done
#pragma unroll
    for (int r = 0; r < 3; ++r)              // regs -> LDS, lane-linear (conflict-free)
      *(bf16x8*)(smem + (size_t)(tid + 512 * r) * 16) = kreg[r];
    __syncthreads();                         // (B) staged
    if (ch < 15) {                           // issue next chunk's loads under compute
#pragma unroll
      for (int r = 0; r < 3; ++r) {
        sp_ptr[r] += sp_str[r];
        kreg[r] = *(const bf16x8*)sp_ptr[r];
      }
    }

    // ---- QK^T (Q in regs, K frag reads lane-contiguous) ----
    f32x4 sacc[4];
#pragma unroll
    for (int n = 0; n < 4; ++n) sacc[n] = (f32x4){0.f, 0.f, 0.f, 0.f};
#pragma unroll
    for (int kb = 0; kb < 3; ++kb) {
#pragma unroll
      for (int n = 0; n < 4; ++n) {
        bf16x8 bfm = *(const bf16x8*)&kt[(size_t)((kb * 4 + n) * 64 + lane) * 8];
        sacc[n] = __builtin_amdgcn_mfma_f32_16x16x32_bf16(qf[kb], bfm, sacc[n], 0, 0, 0);
      }
    }
    if (ch == 15) {                          // mask s >= 1000 (s-local >= 40)
#pragma unroll
      for (int r = 0; r < 4; ++r) {
        if (l15 >= 8) sacc[2][r] = -1e30f;
        sacc[3][r] = -1e30f;
      }
    }

    // ---- register online softmax, exp2 domain ----
    float mc[4];
#pragma unroll
    for (int r = 0; r < 4; ++r) {
      float m0 = fmaxf(fmaxf(sacc[0][r], sacc[1][r]), fmaxf(sacc[2][r], sacc[3][r]));
      m0 = fmaxf(m0, __shfl_xor(m0, 1, 64));
      m0 = fmaxf(m0, __shfl_xor(m0, 2, 64));
      m0 = fmaxf(m0, __shfl_xor(m0, 4, 64));
      m0 = fmaxf(m0, __shfl_xor(m0, 8, 64));
      mc[r] = m0;
    }
    bool keep = (mc[0] - m_run[0] <= 8.f) && (mc[1] - m_run[1] <= 8.f) &&
                (mc[2] - m_run[2] <= 8.f) && (mc[3] - m_run[3] <= 8.f);
    if (!__all(keep)) {                      // defer-max (T13)
#pragma unroll
      for (int r = 0; r < 4; ++r) {
        float mn = fmaxf(m_run[r], mc[r]);
        float al = exp2f(m_run[r] - mn);
        m_run[r] = mn;
        l_run[r] *= al;
#pragma unroll
        for (int n = 0; n < 6; ++n) oacc[n][r] *= al;
      }
    }
    float pr[4][4];                          // [n][r]
#pragma unroll
    for (int r = 0; r < 4; ++r) {
      float ls = 0.f;
#pragma unroll
      for (int n = 0; n < 4; ++n) { pr[n][r] = exp2f(sacc[n][r] - m_run[r]); ls += pr[n][r]; }
      ls += __shfl_xor(ls, 1, 64);
      ls += __shfl_xor(ls, 2, 64);
      ls += __shfl_xor(ls, 4, 64);
      ls += __shfl_xor(ls, 8, 64);
      l_run[r] += ls;
    }

    // ---- P -> sigma-swizzled A-frags in LDS (same-wave, no barrier), then PV ----
#pragma unroll
    for (int kb = 0; kb < 2; ++kb) {
#pragma unroll
      for (int nn = 0; nn < 2; ++nn) {
        int n = kb * 2 + nn;
        int qd2 = (nn << 1) | (l15 >> 3), j = l15 & 7;
#pragma unroll
        for (int r = 0; r < 4; ++r) {
          int g0 = qd2 * 16 + quad * 4 + r;
          int gs = g0 ^ ((g0 >> 3) & 7);     // bank-spread swizzle
          sP[(size_t)(wv * 64 + gs) * 8 + j] = (bf16)pr[n][r];
        }
      }
      int gl = lane ^ ((lane >> 3) & 7);
      bf16x8 pa = *(const bf16x8*)&sP[(size_t)(wv * 64 + gl) * 8];
#pragma unroll
      for (int n2 = 0; n2 < 6; ++n2) {
        bf16x8 vf = *(const bf16x8*)&vt[(size_t)((kb * 6 + n2) * 64 + lane) * 8];
        oacc[n2] = __builtin_amdgcn_mfma_f32_16x16x32_bf16(pa, vf, oacc[n2], 0, 0, 0);
      }
    }
  }

  // ---- epilogue: /l, per-wave bf16 LDS transpose [96][17], coalesced bf16 out ----
  float inv[4];
#pragma unroll
  for (int r = 0; r < 4; ++r) inv[r] = 1.0f / l_run[r];
  __syncthreads();                           // all waves done with kt/vt/sP
  bf16* sOw = (bf16*)smem + wv * (96 * 17);
#pragma unroll
  for (int n2 = 0; n2 < 6; ++n2)
#pragma unroll
    for (int r = 0; r < 4; ++r)
      sOw[(n2 * 16 + l15) * 17 + quad * 4 + r] = (bf16)(oacc[n2][r] * inv[r]);
  // same-wave DS in-order: safe to read back without barrier
#pragma unroll
  for (int r2 = 0; r2 < 24; ++r2) {
    int g = r2 * 64 + lane;                  // 16 t x 96 i, i fast (coalesced out)
    int tl = g / 96, i = g % 96;
    owsT[((size_t)b * T_ + t0 + wv * 16 + tl) * D_ + h * DK + i] = sOw[i * 17 + tl];
  }
}

extern "C" void kernel_launch(void* const* d_in, const int* in_sizes, int n_in,
                              void* d_out, int out_size, void* d_ws, size_t ws_size,
                              hipStream_t stream) {
  const float* z  = (const float*)d_in[0];
  const float* mb = (const float*)d_in[1];
  const float* Wq = (const float*)d_in[2];
  const float* bq = (const float*)d_in[3];
  const float* Wk = (const float*)d_in[4];
  const float* bk = (const float*)d_in[5];
  const float* Wv = (const float*)d_in[6];
  const float* bv = (const float*)d_in[7];
  const float* Wo = (const float*)d_in[8];
  const float* bo = (const float*)d_in[9];
  float* out = (float*)d_out;

  // ws: ktg | vtg | zT | owsT | qws (all bf16)
  bf16* ktg  = (bf16*)d_ws;
  bf16* vtg  = ktg + 2 * SP * DK;
  bf16* zT   = vtg + 2 * DK * SP;
  bf16* owsT = zT + (size_t)B_ * T_ * D_;
  bf16* qws  = owsT + (size_t)B_ * T_ * D_;

  // fused zt (y<16) + kv (y>=16): independent producers, one dispatch
  pre_kernel        <<<dim3(64, 28),          256, 0, stream>>>(z, zT, mb, Wk, bk, Wv, bv,
                                                                ktg, vtg);
  // fold log2e into Q so softmax runs in exp2 domain; q stored bf16
  proj_kernel<bf16> <<<dim3(T_ / 256, 3, B_), 256, 0, stream>>>(zT, Wq, bq, qws,
                                                                SCALE * LOG2E);
  attn_kernel       <<<dim3(T_ / 128, 2, B_), 512, 0, stream>>>(qws, ktg, vtg, owsT);
  proj_kernel<float><<<dim3(T_ / 256, 3, B_), 256, 0, stream>>>(owsT, Wo, bo, out, 1.0f);
}

// Round 4
// 253.864 us; speedup vs baseline: 1.3161x; 1.1141x over previous
//
#include <hip/hip_runtime.h>

// R9: dispatch elimination + MFMA-denominator.
//  - Q-projection fused into attn prologue (36 MFMA/wave, 6-kb staged loop with T14
//    register prefetch, acc scattered into the existing swizzled qt fragments).
//    Removes the q-proj dispatch + qws HBM round trip.
//  - Softmax denominator via ones-B-fragment MFMA (lacc): kills the 16-shfl sum
//    chain per chunk; defer-max rescale applies to lacc uniformly.
//  - Keeps R8: sigma LDS swizzles, reg K/V prefetch, exp2-domain softmax,
//    defer-max THR=8, fused pre (zt+kv), T14-prefetched o-proj.

typedef float  f32x4  __attribute__((ext_vector_type(4)));
typedef __bf16 bf16;
typedef __bf16 bf16x8 __attribute__((ext_vector_type(8)));

#define B_   16
#define D_   192
#define T_   4096
#define BANK 1000
#define SP   1024
#define DK   96
#define SCALE 0.10206207261596577f   // 1/sqrt(96)
#define LOG2E 1.4426950408889634f

// ---------------- fused pre-work: zt (y<16) | kv (y>=16) ----------------
__global__ __launch_bounds__(256) void pre_kernel(
    const float* __restrict__ z, bf16* __restrict__ zT,
    const float* __restrict__ mb,
    const float* __restrict__ Wk, const float* __restrict__ bk,
    const float* __restrict__ Wv, const float* __restrict__ bv,
    bf16* __restrict__ ktg, bf16* __restrict__ vtg) {
  __shared__ __align__(16) bf16 sT[64 * 200];
  const int tid = threadIdx.x;
  if (blockIdx.y < 16) {
    // z transpose: z f32 [b][c][t] -> zT bf16 [b][t][c]
    const int t0 = blockIdx.x * 64, b = blockIdx.y;
#pragma unroll
    for (int it = 0; it < 48; ++it) {        // 192c x 64t, coalesced along t
      int e = tid + 256 * it;
      int c = e >> 6, tl = e & 63;
      sT[tl * 200 + c] = (bf16)z[((size_t)b * D_ + c) * T_ + t0 + tl];
    }
    __syncthreads();
#pragma unroll
    for (int it = 0; it < 6; ++it) {         // 1536 granules of 8 bf16
      int g = tid + 256 * it;
      int tl = g / 24, c8 = (g % 24) * 8;
      bf16x8 v = *(const bf16x8*)&sT[tl * 200 + c8];
      *(bf16x8*)&zT[((size_t)b * T_ + t0 + tl) * D_ + c8] = v;
    }
  } else {
    // K/V projection: ktg [h][1024 s][96 i], vtg [h][96 i][1024 s]
    int idx = (blockIdx.y - 16) * 64 + blockIdx.x;   // 0..767
    int s = (idx & 3) * 256 + tid;
    int o = idx >> 2;
    int h = o / DK, i = o % DK;
    float ak = 0.f, av = 0.f;
    if (s < BANK) {
      ak = bk[o]; av = bv[o];
      for (int c = 0; c < D_; ++c) {
        float m = mb[c * BANK + s];
        ak += Wk[o * D_ + c] * m;
        av += Wv[o * D_ + c] * m;
      }
    }
    ktg[(size_t)(h * SP + s) * DK + i] = (bf16)ak;
    vtg[(size_t)(h * DK + i) * SP + s] = (bf16)av;
  }
}

// ---------------- MFMA projection: Y[b][o][t] = (W · X + bias) * outscale ----------------
// XT bf16 [b][t][192 c]; W f32 [o][c]; Y (f32 or bf16) [b][o][t].
template <typename OT>
__global__ __launch_bounds__(256) void proj_kernel(
    const bf16* __restrict__ XT, const float* __restrict__ W,
    const float* __restrict__ bias, OT* __restrict__ Y, float outscale) {
  __shared__ __align__(16) char smem[40960];
  bf16* sA = (bf16*)smem;                    // per-chunk [16 tg][64 lane][8] = 16384 B
  bf16* sB = (bf16*)(smem + 16384);          // [6 kb][4 nt][64 lane][8]     = 24576 B
  float* sE = (float*)smem;                  // epilogue overlay: 4 waves x [16][68] f32

  const int tid = threadIdx.x;
  const int t0 = blockIdx.x * 256, o0 = blockIdx.y * 64, b = blockIdx.z;
  const int lane = tid & 63, wv = tid >> 6;
  const int quad = lane >> 4, l15 = lane & 15;

  const bf16* ap[4];
#pragma unroll
  for (int r = 0; r < 4; ++r) {
    int g = tid + 256 * r;
    int tg = g >> 6, qd = (g >> 4) & 3, l5 = g & 15;
    ap[r] = &XT[((size_t)b * T_ + t0 + tg * 16 + l5) * D_ + qd * 8];
  }
  bf16x8 areg[4];
#pragma unroll
  for (int r = 0; r < 4; ++r) areg[r] = *(const bf16x8*)ap[r];

#pragma unroll
  for (int r = 0; r < 6; ++r) {
    int g = tid + 256 * r;                   // [kb][nt][lane]
    int kb = g >> 8, nt = (g >> 6) & 3, qd = (g >> 4) & 3, l5 = g & 15;
    const float* wp = &W[(o0 + nt * 16 + l5) * D_ + kb * 32 + qd * 8];
    f32x4 wa = *(const f32x4*)wp, wb = *(const f32x4*)(wp + 4);
    bf16x8 pk;
#pragma unroll
    for (int u = 0; u < 4; ++u) { pk[u] = (bf16)wa[u]; pk[4 + u] = (bf16)wb[u]; }
    *(bf16x8*)&sB[(size_t)g * 8] = pk;
  }

  f32x4 acc[4][4];
#pragma unroll
  for (int m = 0; m < 4; ++m)
#pragma unroll
    for (int n = 0; n < 4; ++n) acc[m][n] = (f32x4){0.f, 0.f, 0.f, 0.f};

  for (int kb = 0; kb < 6; ++kb) {
    __syncthreads();                         // (A) prev compute done (first: covers sB)
#pragma unroll
    for (int r = 0; r < 4; ++r)              // regs -> LDS, lane-linear
      *(bf16x8*)&sA[(size_t)(tid + 256 * r) * 8] = areg[r];
    __syncthreads();                         // (B) staged
    if (kb < 5) {                            // issue next chunk's loads under compute
#pragma unroll
      for (int r = 0; r < 4; ++r)
        areg[r] = *(const bf16x8*)(ap[r] + (kb + 1) * 32);
    }
    bf16x8 bf[4];
#pragma unroll
    for (int n = 0; n < 4; ++n)
      bf[n] = *(const bf16x8*)&sB[(size_t)((kb * 4 + n) * 64 + lane) * 8];
#pragma unroll
    for (int m = 0; m < 4; ++m) {
      bf16x8 af = *(const bf16x8*)&sA[(size_t)((wv * 4 + m) * 64 + lane) * 8];
#pragma unroll
      for (int n = 0; n < 4; ++n)
        acc[m][n] = __builtin_amdgcn_mfma_f32_16x16x32_bf16(af, bf[n], acc[m][n], 0, 0, 0);
    }
  }
  __syncthreads();                           // before epilogue overlay

  float bs[4];
#pragma unroll
  for (int n = 0; n < 4; ++n) bs[n] = bias[o0 + n * 16 + l15];
  float* se = sE + wv * 1088;                // [16 t][68]
#pragma unroll
  for (int m = 0; m < 4; ++m) {
#pragma unroll
    for (int n = 0; n < 4; ++n)
#pragma unroll
      for (int r = 0; r < 4; ++r)
        se[(quad * 4 + r) * 68 + n * 16 + l15] = (acc[m][n][r] + bs[n]) * outscale;
#pragma unroll
    for (int oo = 0; oo < 16; ++oo) {        // same-wave DS in-order: no barrier
      int ol = oo * 4 + quad;
      Y[((size_t)b * D_ + o0 + ol) * T_ + t0 + wv * 64 + m * 16 + l15] =
          (OT)se[l15 * 68 + ol];
    }
  }
}

// ---------------- fused Q-proj + packed-fragment bf16-MFMA flash attention ----------------
// Block = (b, h, 128 t); 8 waves x 16 t. Chunk = 64 s.
// LDS 32768 B main loop: kt 12288 | vt 12288 | sP 8192.
// Prologue overlays: PA 8192 | PB 6144 (q-proj staging), then qt 24576 (Q frags).
__global__ __launch_bounds__(512) void attn_kernel(
    const bf16* __restrict__ zT, const float* __restrict__ Wq,
    const float* __restrict__ bq, const bf16* __restrict__ ktg,
    const bf16* __restrict__ vtg, bf16* __restrict__ owsT) {
  __shared__ __align__(16) char smem[32768];
  bf16* kt = (bf16*)smem;                    // [3 kb][4 n][64][8] = 12288
  bf16* vt = (bf16*)(smem + 12288);          // [2 kb][6 n][64][8] = 12288
  bf16* sP = (bf16*)(smem + 24576);          // [8 wv][64][8]      =  8192
  bf16* qt = (bf16*)smem;                    // Q-frag overlay (24576)
  bf16* PA = (bf16*)smem;                    // q-proj A chunk [8 tg][64][8] = 8192
  bf16* PB = (bf16*)(smem + 8192);           // q-proj B chunk [6 n][64][8]  = 6144

  const int tid = threadIdx.x;
  const int t0 = blockIdx.x * 128, h = blockIdx.y, b = blockIdx.z;
  const int lane = tid & 63, wv = tid >> 6;
  const int quad = lane >> 4, l15 = lane & 15;

  // ======== fused Q projection: Q = (Wq·z + bq) * SCALE*LOG2E ========
  // M=128 t (8 tiles, 1/wave), N=96 i (6 tiles), K=192 (6 kb of 32).
  const bf16* qa_p;
  {
    int tg = tid >> 6, qd = (tid >> 4) & 3, l5 = tid & 15;
    qa_p = &zT[((size_t)b * T_ + t0 + tg * 16 + l5) * D_ + qd * 8];
  }
  const float* wq_p =
      &Wq[(size_t)(h * DK + ((tid >> 6) & 7) * 16 + (tid & 15)) * D_ + ((tid >> 4) & 3) * 8];
  bf16x8 qa_r = *(const bf16x8*)qa_p;
  f32x4 wqa = (f32x4){0.f, 0.f, 0.f, 0.f}, wqb = (f32x4){0.f, 0.f, 0.f, 0.f};
  if (tid < 384) { wqa = *(const f32x4*)wq_p; wqb = *(const f32x4*)(wq_p + 4); }

  f32x4 qacc[6];
#pragma unroll
  for (int n = 0; n < 6; ++n) qacc[n] = (f32x4){0.f, 0.f, 0.f, 0.f};

  for (int kb = 0; kb < 6; ++kb) {
    __syncthreads();                         // prev MFMA reads done
    *(bf16x8*)&PA[(size_t)tid * 8] = qa_r;
    if (tid < 384) {
      bf16x8 pk;
#pragma unroll
      for (int u = 0; u < 4; ++u) { pk[u] = (bf16)wqa[u]; pk[4 + u] = (bf16)wqb[u]; }
      *(bf16x8*)&PB[(size_t)tid * 8] = pk;
    }
    __syncthreads();                         // staged
    if (kb < 5) {                            // prefetch next chunk under MFMA
      qa_r = *(const bf16x8*)(qa_p + (kb + 1) * 32);
      if (tid < 384) {
        wqa = *(const f32x4*)(wq_p + (kb + 1) * 32);
        wqb = *(const f32x4*)(wq_p + (kb + 1) * 32 + 4);
      }
    }
    bf16x8 af = *(const bf16x8*)&PA[(size_t)(wv * 64 + lane) * 8];
#pragma unroll
    for (int n = 0; n < 6; ++n) {
      bf16x8 bfr = *(const bf16x8*)&PB[(size_t)(n * 64 + lane) * 8];
      qacc[n] = __builtin_amdgcn_mfma_f32_16x16x32_bf16(af, bfr, qacc[n], 0, 0, 0);
    }
  }

  // K/V staging pointers + chunk-0 prefetch (latency hides under Q scatter)
  const bf16* kb_g = ktg + (size_t)h * SP * DK;
  const bf16* vb_g = vtg + (size_t)h * DK * SP;
  const bf16* sp_ptr[3];
  int sp_str[3];
#pragma unroll
  for (int r = 0; r < 3; ++r) {
    int g = tid + 512 * r;
    if (g < 768) {                           // K granule
      int kb = g >> 8, n = (g >> 6) & 3, qd = (g >> 4) & 3, l5 = g & 15;
      sp_ptr[r] = kb_g + (size_t)(n * 16 + l5) * DK + kb * 32 + qd * 8;
      sp_str[r] = 64 * DK;
    } else {                                 // V granule
      int gv = g - 768, blk = gv >> 6;
      int kbv = blk / 6, n = blk % 6, qd = (gv >> 4) & 3, l5 = gv & 15;
      sp_ptr[r] = vb_g + (size_t)(n * 16 + l5) * SP + kbv * 32 + qd * 8;
      sp_str[r] = 64;
    }
  }
  bf16x8 kreg[3];
#pragma unroll
  for (int r = 0; r < 3; ++r) kreg[r] = *(const bf16x8*)sp_ptr[r];

  __syncthreads();                           // q-proj LDS reads done -> qt overlay safe
  // bias + scale, scatter acc -> sigma-swizzled qt fragments
#pragma unroll
  for (int n = 0; n < 6; ++n) {
    float bqv = bq[h * DK + n * 16 + l15];
#pragma unroll
    for (int r = 0; r < 4; ++r) {
      float val = (qacc[n][r] + bqv) * (SCALE * LOG2E);
      int i = n * 16 + l15;
      int kbi = i >> 5, qd = (i >> 3) & 3, j = i & 7;
      int G = (kbi * 8 + wv) * 64 + qd * 16 + quad * 4 + r;
      int Gs = G ^ ((G >> 6) & 7);
      qt[(size_t)Gs * 8 + j] = (bf16)val;
    }
  }
  __syncthreads();
  bf16x8 qf[3];
#pragma unroll
  for (int kb = 0; kb < 3; ++kb) {
    int G = (kb * 8 + wv) * 64 + lane;
    int Gs = G ^ ((G >> 6) & 7);
    qf[kb] = *(const bf16x8*)&qt[(size_t)Gs * 8];
  }

  bf16x8 ones;
#pragma unroll
  for (int u = 0; u < 8; ++u) ones[u] = (bf16)1.0f;

  f32x4 oacc[6];
#pragma unroll
  for (int n = 0; n < 6; ++n) oacc[n] = (f32x4){0.f, 0.f, 0.f, 0.f};
  f32x4 lacc = (f32x4){0.f, 0.f, 0.f, 0.f};
  float m_run[4] = {-1e30f, -1e30f, -1e30f, -1e30f};

  for (int ch = 0; ch < 16; ++ch) {
    __syncthreads();                         // (A) prev readers (incl qf) done
#pragma unroll
    for (int r = 0; r < 3; ++r)              // regs -> LDS, lane-linear (conflict-free)
      *(bf16x8*)(smem + (size_t)(tid + 512 * r) * 16) = kreg[r];
    __syncthreads();                         // (B) staged
    if (ch < 15) {                           // issue next chunk's loads under compute
#pragma unroll
      for (int r = 0; r < 3; ++r) {
        sp_ptr[r] += sp_str[r];
        kreg[r] = *(const bf16x8*)sp_ptr[r];
      }
    }

    // ---- QK^T (Q in regs, K frag reads lane-contiguous) ----
    f32x4 sacc[4];
#pragma unroll
    for (int n = 0; n < 4; ++n) sacc[n] = (f32x4){0.f, 0.f, 0.f, 0.f};
#pragma unroll
    for (int kb = 0; kb < 3; ++kb) {
#pragma unroll
      for (int n = 0; n < 4; ++n) {
        bf16x8 bfm = *(const bf16x8*)&kt[(size_t)((kb * 4 + n) * 64 + lane) * 8];
        sacc[n] = __builtin_amdgcn_mfma_f32_16x16x32_bf16(qf[kb], bfm, sacc[n], 0, 0, 0);
      }
    }
    if (ch == 15) {                          // mask s >= 1000 (s-local >= 40)
#pragma unroll
      for (int r = 0; r < 4; ++r) {
        if (l15 >= 8) sacc[2][r] = -1e30f;
        sacc[3][r] = -1e30f;
      }
    }

    // ---- online max (shfl tree), defer-max rescale, exp2 ----
    float mc[4];
#pragma unroll
    for (int r = 0; r < 4; ++r) {
      float m0 = fmaxf(fmaxf(sacc[0][r], sacc[1][r]), fmaxf(sacc[2][r], sacc[3][r]));
      m0 = fmaxf(m0, __shfl_xor(m0, 1, 64));
      m0 = fmaxf(m0, __shfl_xor(m0, 2, 64));
      m0 = fmaxf(m0, __shfl_xor(m0, 4, 64));
      m0 = fmaxf(m0, __shfl_xor(m0, 8, 64));
      mc[r] = m0;
    }
    bool keep = (mc[0] - m_run[0] <= 8.f) && (mc[1] - m_run[1] <= 8.f) &&
                (mc[2] - m_run[2] <= 8.f) && (mc[3] - m_run[3] <= 8.f);
    if (!__all(keep)) {                      // defer-max (T13)
#pragma unroll
      for (int r = 0; r < 4; ++r) {
        float mn = fmaxf(m_run[r], mc[r]);
        float al = exp2f(m_run[r] - mn);
        m_run[r] = mn;
        lacc[r] *= al;
#pragma unroll
        for (int n = 0; n < 6; ++n) oacc[n][r] *= al;
      }
    }
    float pr[4][4];                          // [n][r]
#pragma unroll
    for (int r = 0; r < 4; ++r)
#pragma unroll
      for (int n = 0; n < 4; ++n) pr[n][r] = exp2f(sacc[n][r] - m_run[r]);

    // ---- P -> sigma-swizzled A-frags (same-wave, no barrier), PV + MFMA row-sum ----
#pragma unroll
    for (int kb = 0; kb < 2; ++kb) {
#pragma unroll
      for (int nn = 0; nn < 2; ++nn) {
        int n = kb * 2 + nn;
        int qd2 = (nn << 1) | (l15 >> 3), j = l15 & 7;
#pragma unroll
        for (int r = 0; r < 4; ++r) {
          int g0 = qd2 * 16 + quad * 4 + r;
          int gs = g0 ^ ((g0 >> 3) & 7);     // bank-spread swizzle
          sP[(size_t)(wv * 64 + gs) * 8 + j] = (bf16)pr[n][r];
        }
      }
      int gl = lane ^ ((lane >> 3) & 7);
      bf16x8 pa = *(const bf16x8*)&sP[(size_t)(wv * 64 + gl) * 8];
      lacc = __builtin_amdgcn_mfma_f32_16x16x32_bf16(pa, ones, lacc, 0, 0, 0);
#pragma unroll
      for (int n2 = 0; n2 < 6; ++n2) {
        bf16x8 vf = *(const bf16x8*)&vt[(size_t)((kb * 6 + n2) * 64 + lane) * 8];
        oacc[n2] = __builtin_amdgcn_mfma_f32_16x16x32_bf16(pa, vf, oacc[n2], 0, 0, 0);
      }
    }
  }

  // ---- epilogue: /l, per-wave bf16 LDS transpose [96][17], coalesced bf16 out ----
  float inv[4];
#pragma unroll
  for (int r = 0; r < 4; ++r) inv[r] = 1.0f / lacc[r];
  __syncthreads();                           // all waves done with kt/vt/sP
  bf16* sOw = (bf16*)smem + wv * (96 * 17);
#pragma unroll
  for (int n2 = 0; n2 < 6; ++n2)
#pragma unroll
    for (int r = 0; r < 4; ++r)
      sOw[(n2 * 16 + l15) * 17 + quad * 4 + r] = (bf16)(oacc[n2][r] * inv[r]);
  // same-wave DS in-order: safe to read back without barrier
#pragma unroll
  for (int r2 = 0; r2 < 24; ++r2) {
    int g = r2 * 64 + lane;                  // 16 t x 96 i, i fast (coalesced out)
    int tl = g / 96, i = g % 96;
    owsT[((size_t)b * T_ + t0 + wv * 16 + tl) * D_ + h * DK + i] = sOw[i * 17 + tl];
  }
}

extern "C" void kernel_launch(void* const* d_in, const int* in_sizes, int n_in,
                              void* d_out, int out_size, void* d_ws, size_t ws_size,
                              hipStream_t stream) {
  const float* z  = (const float*)d_in[0];
  const float* mb = (const float*)d_in[1];
  const float* Wq = (const float*)d_in[2];
  const float* bq = (const float*)d_in[3];
  const float* Wk = (const float*)d_in[4];
  const float* bk = (const float*)d_in[5];
  const float* Wv = (const float*)d_in[6];
  const float* bv = (const float*)d_in[7];
  const float* Wo = (const float*)d_in[8];
  const float* bo = (const float*)d_in[9];
  float* out = (float*)d_out;

  // ws: ktg | vtg | zT | owsT (all bf16)
  bf16* ktg  = (bf16*)d_ws;
  bf16* vtg  = ktg + 2 * SP * DK;
  bf16* zT   = vtg + 2 * DK * SP;
  bf16* owsT = zT + (size_t)B_ * T_ * D_;

  // fused zt (y<16) + kv (y>=16): independent producers, one dispatch
  pre_kernel        <<<dim3(64, 28),          256, 0, stream>>>(z, zT, mb, Wk, bk, Wv, bv,
                                                                ktg, vtg);
  // attn with fused Q-projection (SCALE*LOG2E folded at the scatter)
  attn_kernel       <<<dim3(T_ / 128, 2, B_), 512, 0, stream>>>(zT, Wq, bq, ktg, vtg, owsT);
  proj_kernel<float><<<dim3(T_ / 256, 3, B_), 256, 0, stream>>>(owsT, Wo, bo, out, 1.0f);
}